// Round 4
// baseline (343.278 us; speedup 1.0000x reference)
//
#include <hip/hip_runtime.h>

// GraphFilter B=16,T=64,F=64,N=128,E=2,K=4 — lean bf16 MFMA pipeline v2.
//   P3[s] = U3[s]
//   W2[s] = U2[s] + P3[s-1]@S[s]
//   W1[s] = U1[s] + W2[s-1]@S[s]
//   y[t]  = bias + sum_e ( U0[t] + W1[t-1]@S[t] )
// U_k[s][o][n] = sum_f H[o,e,k,f] x[s,f,n]
// Pre-converted: Hb bf16 [e][k][o][f]; xT bf16 [b,s][n][f]; ST bf16 [b,s,e][n][m].
// A-fragments (H, Pin) load global->reg directly (layouts are A-operand-ready);
// LDS holds only the S^T tile; one __syncthreads per step block.

namespace {
constexpr int B = 16, T = 64, F = 64, N = 128, E = 2, K = 4;
constexpr int SS = 136;   // sS stride in ushorts (128 + 8 pad)
}

typedef short v8s __attribute__((ext_vector_type(8)));
typedef float v4f __attribute__((ext_vector_type(4)));

__device__ inline ushort f2bf(float f) {
  union { float f; uint u; } v; v.f = f;
  uint u = v.u;
  return (ushort)((u + 0x7fffu + ((u >> 16) & 1u)) >> 16);
}

// ---- H: fp32 [o][e][k][f] -> bf16 [e][k][o][f] ----
__global__ __launch_bounds__(256) void cvt_H(const float* __restrict__ H,
                                             ushort* __restrict__ Hb) {
  const int d4 = blockIdx.x * 256 + threadIdx.x;
  const int d = d4 * 4;
  const int f = d & 63, o = (d >> 6) & 63, k = (d >> 12) & 3, e = (d >> 14) & 1;
  const float4 v = *(const float4*)(H + (((size_t)o * E + e) * K + k) * F + f);
  uint2 w;
  w.x = (uint)f2bf(v.x) | ((uint)f2bf(v.y) << 16);
  w.y = (uint)f2bf(v.z) | ((uint)f2bf(v.w) << 16);
  *(uint2*)(Hb + d) = w;
}

// ---- x: fp32 [b,s][f][n] -> bf16 xT [b,s][n][f] ----
__global__ __launch_bounds__(256) void cvt_X(const float* __restrict__ x,
                                             ushort* __restrict__ xT) {
  __shared__ ushort tile[64 * 130];
  const int bid = blockIdx.x;               // b*T+s
  const float* xg = x + (size_t)bid * F * N;
  ushort* Og = xT + (size_t)bid * N * F;
  const int tid = threadIdx.x;
  #pragma unroll
  for (int it = 0; it < 8; ++it) {
    const int idx = tid + it * 256;         // 0..2047
    const int f = idx >> 5, n4 = (idx & 31) * 4;
    const float4 v = *(const float4*)(xg + f * N + n4);
    uint* lp = (uint*)&tile[f * 130 + n4];
    lp[0] = (uint)f2bf(v.x) | ((uint)f2bf(v.y) << 16);
    lp[1] = (uint)f2bf(v.z) | ((uint)f2bf(v.w) << 16);
  }
  __syncthreads();
  #pragma unroll
  for (int it = 0; it < 4; ++it) {
    const int idx = tid + it * 256;         // 0..1023
    const int n = idx >> 3, f8 = (idx & 7) * 8;
    ushort p[8];
    #pragma unroll
    for (int j = 0; j < 8; ++j) p[j] = tile[(f8 + j) * 130 + n];
    uint4 w;
    w.x = (uint)p[0] | ((uint)p[1] << 16);
    w.y = (uint)p[2] | ((uint)p[3] << 16);
    w.z = (uint)p[4] | ((uint)p[5] << 16);
    w.w = (uint)p[6] | ((uint)p[7] << 16);
    *(uint4*)(Og + n * F + f8) = w;
  }
}

// ---- S: fp32 [m][n] -> bf16 [n][m] ----
__global__ __launch_bounds__(256) void cvt_S(const float* __restrict__ S,
                                             ushort* __restrict__ ST) {
  __shared__ ushort tile[128 * 130];
  const int bid = blockIdx.x;               // (b*T+s)*E+e
  const float* Sg = S + (size_t)bid * N * N;
  ushort* Og = ST + (size_t)bid * N * N;
  const int tid = threadIdx.x;
  #pragma unroll
  for (int it = 0; it < 16; ++it) {
    const int idx = tid + it * 256;
    const int m = idx >> 5, n4 = (idx & 31) * 4;
    const float4 v = *(const float4*)(Sg + m * N + n4);
    uint* lp = (uint*)&tile[m * 130 + n4];
    lp[0] = (uint)f2bf(v.x) | ((uint)f2bf(v.y) << 16);
    lp[1] = (uint)f2bf(v.z) | ((uint)f2bf(v.w) << 16);
  }
  __syncthreads();
  #pragma unroll
  for (int it = 0; it < 8; ++it) {
    const int idx = tid + it * 256;         // 0..2047
    const int n = idx >> 4, m8 = (idx & 15) * 8;
    ushort p[8];
    #pragma unroll
    for (int j = 0; j < 8; ++j) p[j] = tile[(m8 + j) * 130 + n];
    uint4 w;
    w.x = (uint)p[0] | ((uint)p[1] << 16);
    w.y = (uint)p[2] | ((uint)p[3] << 16);
    w.z = (uint)p[4] | ((uint)p[5] << 16);
    w.w = (uint)p[6] | ((uint)p[7] << 16);
    *(uint4*)(Og + n * N + m8) = w;
  }
}

// ---- fragment helpers ----
__device__ inline void load_hf(const ushort* __restrict__ Hb, int e, int k,
                               int ob0, int l15, int q, v8s hf[2][2]) {
  #pragma unroll
  for (int mt = 0; mt < 2; ++mt)
    #pragma unroll
    for (int fk = 0; fk < 2; ++fk)
      hf[mt][fk] = *(const v8s*)(Hb +
          ((size_t)((e * K + k) * 64 + ob0 + 16 * mt + l15)) * 64 + fk * 32 + q * 8);
}

__device__ inline void load_xf(const ushort* __restrict__ xb,
                               int nb0, int l15, int q, v8s xf[4][2]) {
  #pragma unroll
  for (int nt = 0; nt < 4; ++nt)
    #pragma unroll
    for (int fk = 0; fk < 2; ++fk)
      xf[nt][fk] = *(const v8s*)(xb + (nb0 + 16 * nt + l15) * F + fk * 32 + q * 8);
}

__device__ inline void load_pf(const ushort* __restrict__ Pg,
                               int ob0, int l15, int q, v8s pf[2][2][2]) {
  #pragma unroll
  for (int mt = 0; mt < 2; ++mt)
    #pragma unroll
    for (int h = 0; h < 2; ++h)
      #pragma unroll
      for (int lk = 0; lk < 2; ++lk)
        pf[mt][h][lk] = *(const v8s*)(Pg +
            (ob0 + 16 * mt + l15) * N + h * 64 + lk * 32 + q * 8);
}

__device__ inline void stage_S(const ushort* __restrict__ STg, ushort* sS, int tid) {
  #pragma unroll
  for (int it = 0; it < 8; ++it) {
    const int idx = tid + it * 256;         // 0..2047
    const int n = idx >> 4, m8 = (idx & 15) * 8;
    *(uint4*)&sS[n * SS + m8] = *(const uint4*)(STg + n * N + m8);
  }
}

__device__ inline void zero_acc(v4f acc[2][4]) {
  #pragma unroll
  for (int i = 0; i < 2; ++i)
    #pragma unroll
    for (int j = 0; j < 4; ++j) {
      acc[i][j][0] = 0.f; acc[i][j][1] = 0.f; acc[i][j][2] = 0.f; acc[i][j][3] = 0.f;
    }
}

__device__ inline void do_proj(const v8s hf[2][2], const v8s xf[4][2],
                               v4f acc[2][4]) {
  #pragma unroll
  for (int fk = 0; fk < 2; ++fk)
    #pragma unroll
    for (int mt = 0; mt < 2; ++mt)
      #pragma unroll
      for (int nt = 0; nt < 4; ++nt)
        acc[mt][nt] = __builtin_amdgcn_mfma_f32_16x16x32_bf16(
            hf[mt][fk], xf[nt][fk], acc[mt][nt], 0, 0, 0);
}

__device__ inline void do_mm(const v8s pf[2][2][2], const ushort* sS,
                             v4f acc[2][4], int nb0, int l15, int q) {
  #pragma unroll
  for (int h = 0; h < 2; ++h)
    #pragma unroll
    for (int lk = 0; lk < 2; ++lk) {
      v8s bb[4];
      #pragma unroll
      for (int nt = 0; nt < 4; ++nt)
        bb[nt] = *(const v8s*)&sS[(nb0 + 16 * nt + l15) * SS + h * 64 + lk * 32 + q * 8];
      #pragma unroll
      for (int mt = 0; mt < 2; ++mt)
        #pragma unroll
        for (int nt = 0; nt < 4; ++nt)
          acc[mt][nt] = __builtin_amdgcn_mfma_f32_16x16x32_bf16(
              pf[mt][h][lk], bb[nt], acc[mt][nt], 0, 0, 0);
    }
}

__device__ inline void store_W(ushort* __restrict__ Og, v4f acc[2][4],
                               int ob0, int nb0, int l15, int q) {
  #pragma unroll
  for (int mt = 0; mt < 2; ++mt)
    #pragma unroll
    for (int nt = 0; nt < 4; ++nt) {
      const int col = nb0 + 16 * nt + l15;
      #pragma unroll
      for (int r = 0; r < 4; ++r)
        Og[(ob0 + 16 * mt + q * 4 + r) * N + col] = f2bf(acc[mt][nt][r]);
    }
}

// ---- pure projection pass: Out[b,s,e] = U_k[b,s,e] ----
__global__ __launch_bounds__(256, 4) void gf_proj(
    const ushort* __restrict__ xT, const ushort* __restrict__ Hb,
    ushort* __restrict__ Out, int k) {
  const int bid = blockIdx.x;
  const int e = bid & 1, bs = bid >> 1;
  const int tid = threadIdx.x, w = tid >> 6, lane = tid & 63;
  const int l15 = lane & 15, q = lane >> 4;
  const int ob0 = (w & 1) * 32, nb0 = (w >> 1) * 64;
  v8s hf[2][2], xf[4][2];
  load_hf(Hb, e, k, ob0, l15, q, hf);
  load_xf(xT + (size_t)bs * N * F, nb0, l15, q, xf);
  v4f acc[2][4];
  zero_acc(acc);
  do_proj(hf, xf, acc);
  store_W(Out + (size_t)bid * F * N, acc, ob0, nb0, l15, q);
}

// ---- step: Out[b,s,e] = U_k[b,s,e] + Pin[b,s-1,e]@S[b,s,e] ----
__global__ __launch_bounds__(256, 4) void gf_step(
    const ushort* __restrict__ xT, const ushort* __restrict__ ST,
    const ushort* __restrict__ Hb, const ushort* __restrict__ Pin,
    ushort* __restrict__ Out, int k) {
  __shared__ ushort sS[128 * SS];   // 34.8 KB -> 4 blocks/CU
  const int bid = blockIdx.x;
  const int e = bid & 1, bs = bid >> 1;
  const int s = bs & (T - 1);
  const int tid = threadIdx.x, w = tid >> 6, lane = tid & 63;
  const int l15 = lane & 15, q = lane >> 4;
  const int ob0 = (w & 1) * 32, nb0 = (w >> 1) * 64;
  const bool has_p = (s > 0);

  if (has_p) stage_S(ST + (size_t)bid * N * N, sS, tid);

  v8s hf[2][2], xf[4][2];
  load_hf(Hb, e, k, ob0, l15, q, hf);
  load_xf(xT + (size_t)bs * N * F, nb0, l15, q, xf);

  v4f acc[2][4];
  zero_acc(acc);
  do_proj(hf, xf, acc);

  if (has_p) {
    v8s pf[2][2][2];
    load_pf(Pin + (size_t)((bs - 1) * E + e) * F * N, ob0, l15, q, pf);
    __syncthreads();
    do_mm(pf, sS, acc, nb0, l15, q);
  }
  store_W(Out + (size_t)bid * F * N, acc, ob0, nb0, l15, q);
}

// ---- final: y[b,t] = bias + sum_e ( U0 + W1[t-1]@S[t] ) ----
__global__ __launch_bounds__(256, 4) void gf_final(
    const ushort* __restrict__ xT, const ushort* __restrict__ ST,
    const ushort* __restrict__ Hb, const ushort* __restrict__ Pin,
    const float* __restrict__ bias, float* __restrict__ y) {
  __shared__ ushort sS[128 * SS];
  const int bid = blockIdx.x;               // b*T+t
  const int t = bid & (T - 1);
  const int tid = threadIdx.x, w = tid >> 6, lane = tid & 63;
  const int l15 = lane & 15, q = lane >> 4;
  const int ob0 = (w & 1) * 32, nb0 = (w >> 1) * 64;
  const bool has_p = (t > 0);

  v4f acc[2][4];
  zero_acc(acc);

  #pragma unroll
  for (int e = 0; e < E; ++e) {
    if (has_p) {
      if (e > 0) __syncthreads();           // previous e's readers done
      stage_S(ST + (size_t)(bid * E + e) * N * N, sS, tid);
    }
    v8s hf[2][2], xf[4][2];
    load_hf(Hb, e, 0, ob0, l15, q, hf);
    load_xf(xT + (size_t)bid * N * F, nb0, l15, q, xf);
    do_proj(hf, xf, acc);
    if (has_p) {
      v8s pf[2][2][2];
      load_pf(Pin + (size_t)((bid - 1) * E + e) * F * N, ob0, l15, q, pf);
      __syncthreads();
      do_mm(pf, sS, acc, nb0, l15, q);
    }
  }

  float* yg = y + (size_t)bid * F * N;
  #pragma unroll
  for (int mt = 0; mt < 2; ++mt)
    #pragma unroll
    for (int nt = 0; nt < 4; ++nt) {
      const int col = nb0 + 16 * nt + l15;
      #pragma unroll
      for (int r = 0; r < 4; ++r) {
        const int row = ob0 + 16 * mt + q * 4 + r;
        yg[row * N + col] = acc[mt][nt][r] + bias[row];
      }
    }
}

extern "C" void kernel_launch(void* const* d_in, const int* in_sizes, int n_in,
                              void* d_out, int out_size, void* d_ws, size_t ws_size,
                              hipStream_t stream) {
  const float* x    = (const float*)d_in[0];
  const float* S    = (const float*)d_in[1];
  const float* H    = (const float*)d_in[2];
  const float* bias = (const float*)d_in[3];
  float* y = (float*)d_out;

  const size_t STn = (size_t)B * T * E * N * N;   // 33.55M ushorts (64 MB)
  const size_t XTn = (size_t)B * T * N * F;       //  8.39M ushorts (16 MB)
  const size_t Wn  = (size_t)B * T * E * F * N;   // 16.78M ushorts (32 MB)
  ushort* ST = (ushort*)d_ws;
  ushort* xT = ST + STn;
  ushort* Wa = xT + XTn;
  ushort* Wb = Wa + Wn;
  ushort* Hb = Wb + Wn;                           // 32768 ushorts

  cvt_H   <<<32,        256, 0, stream>>>(H, Hb);
  cvt_X   <<<B * T,     256, 0, stream>>>(x, xT);
  cvt_S   <<<B * T * E, 256, 0, stream>>>(S, ST);
  gf_proj <<<B * T * E, 256, 0, stream>>>(xT, Hb, Wa, 3);
  gf_step <<<B * T * E, 256, 0, stream>>>(xT, ST, Hb, Wa, Wb, 2);
  gf_step <<<B * T * E, 256, 0, stream>>>(xT, ST, Hb, Wb, Wa, 1);
  gf_final<<<B * T,     256, 0, stream>>>(xT, ST, Hb, Wa, bias, y);
}

// Round 5
// 342.562 us; speedup vs baseline: 1.0021x; 1.0021x over previous
//
#include <hip/hip_runtime.h>

// GraphFilter B=16,T=64,F=64,N=128,E=2,K=4 — bf16 MFMA pipeline v3.
//   P3[s] = U3[s]
//   W2[s] = U2[s] + P3[s-1]@S[s]
//   W1[s] = U1[s] + W2[s-1]@S[s]
//   y[t]  = bias + sum_e ( U0[t] + W1[t-1]@S[t] )
// U_k[s][o][n] = sum_f H[o,e,k,f] x[s,f,n]
// v3: cvt_S / cvt_X rebuilt as XOR-swizzled vector transposes (b128-only LDS,
// 8x8 register-block transpose, coalesced uint4 global I/O). Round-4 passes kept.

namespace {
constexpr int B = 16, T = 64, F = 64, N = 128, E = 2, K = 4;
constexpr int SS = 136;   // sS stride in ushorts (128 + 8 pad)
}

typedef short v8s __attribute__((ext_vector_type(8)));
typedef float v4f __attribute__((ext_vector_type(4)));

__device__ inline ushort f2bf(float f) {
  union { float f; uint u; } v; v.f = f;
  uint u = v.u;
  return (ushort)((u + 0x7fffu + ((u >> 16) & 1u)) >> 16);
}

__device__ inline uint pk2(float a, float b) {
  return (uint)f2bf(a) | ((uint)f2bf(b) << 16);
}

// ---- H: fp32 [o][e][k][f] -> bf16 [e][k][o][f] ----
__global__ __launch_bounds__(256) void cvt_H(const float* __restrict__ H,
                                             ushort* __restrict__ Hb) {
  const int d4 = blockIdx.x * 256 + threadIdx.x;
  const int d = d4 * 4;
  const int f = d & 63, o = (d >> 6) & 63, k = (d >> 12) & 3, e = (d >> 14) & 1;
  const float4 v = *(const float4*)(H + (((size_t)o * E + e) * K + k) * F + f);
  uint2 w;
  w.x = pk2(v.x, v.y);
  w.y = pk2(v.z, v.w);
  *(uint2*)(Hb + d) = w;
}

// ---- S: fp32 [m][n] -> bf16 [n][m], swizzled vector transpose ----
// LDS layout: element (m,n) at m*128 + ((g ^ (m>>3))*8 + (n&7)), g = n>>3.
__global__ __launch_bounds__(256) void cvt_S(const float* __restrict__ S,
                                             ushort* __restrict__ ST) {
  __shared__ ushort tile[128 * 128];   // 32 KB
  const int bid = blockIdx.x;          // (b*T+s)*E+e
  const float* Sg = S + (size_t)bid * N * N;
  ushort* Og = ST + (size_t)bid * N * N;
  const int tid = threadIdx.x;
  // phase 1: coalesced global read, convert, b128 LDS write (swizzled)
  #pragma unroll
  for (int it = 0; it < 8; ++it) {
    const int idx = tid + it * 256;    // 0..2047 over (m, g)
    const int m = idx >> 4, g = idx & 15;
    const float4 v0 = *(const float4*)(Sg + m * N + g * 8);
    const float4 v1 = *(const float4*)(Sg + m * N + g * 8 + 4);
    uint4 w;
    w.x = pk2(v0.x, v0.y); w.y = pk2(v0.z, v0.w);
    w.z = pk2(v1.x, v1.y); w.w = pk2(v1.z, v1.w);
    const int gp = g ^ (m >> 3);
    *(uint4*)&tile[m * 128 + gp * 8] = w;
  }
  __syncthreads();
  // phase 2: b128 LDS reads (conflict-min), 8x8 register transpose, uint4 stores
  const int a = tid & 15, b = tid >> 4;   // a: m-group, b: n-group
  v8s rows[8];
  #pragma unroll
  for (int j = 0; j < 8; ++j)
    rows[j] = *(const v8s*)&tile[(8 * a + j) * 128 + ((b ^ a) * 8)];
  #pragma unroll
  for (int i = 0; i < 8; ++i) {
    uint4 w;
    w.x = (uint)(ushort)rows[0][i] | ((uint)(ushort)rows[1][i] << 16);
    w.y = (uint)(ushort)rows[2][i] | ((uint)(ushort)rows[3][i] << 16);
    w.z = (uint)(ushort)rows[4][i] | ((uint)(ushort)rows[5][i] << 16);
    w.w = (uint)(ushort)rows[6][i] | ((uint)(ushort)rows[7][i] << 16);
    *(uint4*)(Og + (8 * b + i) * N + 8 * a) = w;
  }
}

// ---- x: fp32 [b,s][f][n] -> bf16 xT [b,s][n][f], same technique ----
// LDS: element (f,n) at f*128 + ((g ^ (f>>3))*8 + (n&7)), g = n>>3 (f>>3 in 0..7).
__global__ __launch_bounds__(256) void cvt_X(const float* __restrict__ x,
                                             ushort* __restrict__ xT) {
  __shared__ ushort tile[64 * 128];    // 16 KB
  const int bid = blockIdx.x;          // b*T+s
  const float* xg = x + (size_t)bid * F * N;
  ushort* Og = xT + (size_t)bid * N * F;
  const int tid = threadIdx.x;
  #pragma unroll
  for (int it = 0; it < 4; ++it) {
    const int idx = tid + it * 256;    // 0..1023 over (f, g)
    const int f = idx >> 4, g = idx & 15;
    const float4 v0 = *(const float4*)(xg + f * N + g * 8);
    const float4 v1 = *(const float4*)(xg + f * N + g * 8 + 4);
    uint4 w;
    w.x = pk2(v0.x, v0.y); w.y = pk2(v0.z, v0.w);
    w.z = pk2(v1.x, v1.y); w.w = pk2(v1.z, v1.w);
    const int gp = g ^ (f >> 3);
    *(uint4*)&tile[f * 128 + gp * 8] = w;
  }
  __syncthreads();
  if (tid < 128) {
    const int a = tid & 7, b = tid >> 3;   // a: f-group (0..7), b: n-group (0..15)
    v8s rows[8];
    #pragma unroll
    for (int j = 0; j < 8; ++j)
      rows[j] = *(const v8s*)&tile[(8 * a + j) * 128 + ((b ^ a) * 8)];
    #pragma unroll
    for (int i = 0; i < 8; ++i) {
      uint4 w;
      w.x = (uint)(ushort)rows[0][i] | ((uint)(ushort)rows[1][i] << 16);
      w.y = (uint)(ushort)rows[2][i] | ((uint)(ushort)rows[3][i] << 16);
      w.z = (uint)(ushort)rows[4][i] | ((uint)(ushort)rows[5][i] << 16);
      w.w = (uint)(ushort)rows[6][i] | ((uint)(ushort)rows[7][i] << 16);
      *(uint4*)(Og + (8 * b + i) * F + 8 * a) = w;
    }
  }
}

// ---- fragment helpers ----
__device__ inline void load_hf(const ushort* __restrict__ Hb, int e, int k,
                               int ob0, int l15, int q, v8s hf[2][2]) {
  #pragma unroll
  for (int mt = 0; mt < 2; ++mt)
    #pragma unroll
    for (int fk = 0; fk < 2; ++fk)
      hf[mt][fk] = *(const v8s*)(Hb +
          ((size_t)((e * K + k) * 64 + ob0 + 16 * mt + l15)) * 64 + fk * 32 + q * 8);
}

__device__ inline void load_xf(const ushort* __restrict__ xb,
                               int nb0, int l15, int q, v8s xf[4][2]) {
  #pragma unroll
  for (int nt = 0; nt < 4; ++nt)
    #pragma unroll
    for (int fk = 0; fk < 2; ++fk)
      xf[nt][fk] = *(const v8s*)(xb + (nb0 + 16 * nt + l15) * F + fk * 32 + q * 8);
}

__device__ inline void load_pf(const ushort* __restrict__ Pg,
                               int ob0, int l15, int q, v8s pf[2][2][2]) {
  #pragma unroll
  for (int mt = 0; mt < 2; ++mt)
    #pragma unroll
    for (int h = 0; h < 2; ++h)
      #pragma unroll
      for (int lk = 0; lk < 2; ++lk)
        pf[mt][h][lk] = *(const v8s*)(Pg +
            (ob0 + 16 * mt + l15) * N + h * 64 + lk * 32 + q * 8);
}

__device__ inline void stage_S(const ushort* __restrict__ STg, ushort* sS, int tid) {
  #pragma unroll
  for (int it = 0; it < 8; ++it) {
    const int idx = tid + it * 256;         // 0..2047
    const int n = idx >> 4, m8 = (idx & 15) * 8;
    *(uint4*)&sS[n * SS + m8] = *(const uint4*)(STg + n * N + m8);
  }
}

__device__ inline void zero_acc(v4f acc[2][4]) {
  #pragma unroll
  for (int i = 0; i < 2; ++i)
    #pragma unroll
    for (int j = 0; j < 4; ++j) {
      acc[i][j][0] = 0.f; acc[i][j][1] = 0.f; acc[i][j][2] = 0.f; acc[i][j][3] = 0.f;
    }
}

__device__ inline void do_proj(const v8s hf[2][2], const v8s xf[4][2],
                               v4f acc[2][4]) {
  #pragma unroll
  for (int fk = 0; fk < 2; ++fk)
    #pragma unroll
    for (int mt = 0; mt < 2; ++mt)
      #pragma unroll
      for (int nt = 0; nt < 4; ++nt)
        acc[mt][nt] = __builtin_amdgcn_mfma_f32_16x16x32_bf16(
            hf[mt][fk], xf[nt][fk], acc[mt][nt], 0, 0, 0);
}

__device__ inline void do_mm(const v8s pf[2][2][2], const ushort* sS,
                             v4f acc[2][4], int nb0, int l15, int q) {
  #pragma unroll
  for (int h = 0; h < 2; ++h)
    #pragma unroll
    for (int lk = 0; lk < 2; ++lk) {
      v8s bb[4];
      #pragma unroll
      for (int nt = 0; nt < 4; ++nt)
        bb[nt] = *(const v8s*)&sS[(nb0 + 16 * nt + l15) * SS + h * 64 + lk * 32 + q * 8];
      #pragma unroll
      for (int mt = 0; mt < 2; ++mt)
        #pragma unroll
        for (int nt = 0; nt < 4; ++nt)
          acc[mt][nt] = __builtin_amdgcn_mfma_f32_16x16x32_bf16(
              pf[mt][h][lk], bb[nt], acc[mt][nt], 0, 0, 0);
    }
}

__device__ inline void store_W(ushort* __restrict__ Og, v4f acc[2][4],
                               int ob0, int nb0, int l15, int q) {
  #pragma unroll
  for (int mt = 0; mt < 2; ++mt)
    #pragma unroll
    for (int nt = 0; nt < 4; ++nt) {
      const int col = nb0 + 16 * nt + l15;
      #pragma unroll
      for (int r = 0; r < 4; ++r)
        Og[(ob0 + 16 * mt + q * 4 + r) * N + col] = f2bf(acc[mt][nt][r]);
    }
}

// ---- pure projection pass: Out[b,s,e] = U_k[b,s,e] ----
__global__ __launch_bounds__(256, 4) void gf_proj(
    const ushort* __restrict__ xT, const ushort* __restrict__ Hb,
    ushort* __restrict__ Out, int k) {
  const int bid = blockIdx.x;
  const int e = bid & 1, bs = bid >> 1;
  const int tid = threadIdx.x, w = tid >> 6, lane = tid & 63;
  const int l15 = lane & 15, q = lane >> 4;
  const int ob0 = (w & 1) * 32, nb0 = (w >> 1) * 64;
  v8s hf[2][2], xf[4][2];
  load_hf(Hb, e, k, ob0, l15, q, hf);
  load_xf(xT + (size_t)bs * N * F, nb0, l15, q, xf);
  v4f acc[2][4];
  zero_acc(acc);
  do_proj(hf, xf, acc);
  store_W(Out + (size_t)bid * F * N, acc, ob0, nb0, l15, q);
}

// ---- step: Out[b,s,e] = U_k[b,s,e] + Pin[b,s-1,e]@S[b,s,e] ----
__global__ __launch_bounds__(256, 4) void gf_step(
    const ushort* __restrict__ xT, const ushort* __restrict__ ST,
    const ushort* __restrict__ Hb, const ushort* __restrict__ Pin,
    ushort* __restrict__ Out, int k) {
  __shared__ ushort sS[128 * SS];   // 34.8 KB -> 4 blocks/CU
  const int bid = blockIdx.x;
  const int e = bid & 1, bs = bid >> 1;
  const int s = bs & (T - 1);
  const int tid = threadIdx.x, w = tid >> 6, lane = tid & 63;
  const int l15 = lane & 15, q = lane >> 4;
  const int ob0 = (w & 1) * 32, nb0 = (w >> 1) * 64;
  const bool has_p = (s > 0);

  if (has_p) stage_S(ST + (size_t)bid * N * N, sS, tid);

  v8s hf[2][2], xf[4][2];
  load_hf(Hb, e, k, ob0, l15, q, hf);
  load_xf(xT + (size_t)bs * N * F, nb0, l15, q, xf);

  v4f acc[2][4];
  zero_acc(acc);
  do_proj(hf, xf, acc);

  if (has_p) {
    v8s pf[2][2][2];
    load_pf(Pin + (size_t)((bs - 1) * E + e) * F * N, ob0, l15, q, pf);
    __syncthreads();
    do_mm(pf, sS, acc, nb0, l15, q);
  }
  store_W(Out + (size_t)bid * F * N, acc, ob0, nb0, l15, q);
}

// ---- final: y[b,t] = bias + sum_e ( U0 + W1[t-1]@S[t] ) ----
__global__ __launch_bounds__(256, 4) void gf_final(
    const ushort* __restrict__ xT, const ushort* __restrict__ ST,
    const ushort* __restrict__ Hb, const ushort* __restrict__ Pin,
    const float* __restrict__ bias, float* __restrict__ y) {
  __shared__ ushort sS[128 * SS];
  const int bid = blockIdx.x;               // b*T+t
  const int t = bid & (T - 1);
  const int tid = threadIdx.x, w = tid >> 6, lane = tid & 63;
  const int l15 = lane & 15, q = lane >> 4;
  const int ob0 = (w & 1) * 32, nb0 = (w >> 1) * 64;
  const bool has_p = (t > 0);

  v4f acc[2][4];
  zero_acc(acc);

  #pragma unroll
  for (int e = 0; e < E; ++e) {
    if (has_p) {
      if (e > 0) __syncthreads();           // previous e's readers done
      stage_S(ST + (size_t)(bid * E + e) * N * N, sS, tid);
    }
    v8s hf[2][2], xf[4][2];
    load_hf(Hb, e, 0, ob0, l15, q, hf);
    load_xf(xT + (size_t)bid * N * F, nb0, l15, q, xf);
    do_proj(hf, xf, acc);
    if (has_p) {
      v8s pf[2][2][2];
      load_pf(Pin + (size_t)((bid - 1) * E + e) * F * N, ob0, l15, q, pf);
      __syncthreads();
      do_mm(pf, sS, acc, nb0, l15, q);
    }
  }

  float* yg = y + (size_t)bid * F * N;
  #pragma unroll
  for (int mt = 0; mt < 2; ++mt)
    #pragma unroll
    for (int nt = 0; nt < 4; ++nt) {
      const int col = nb0 + 16 * nt + l15;
      #pragma unroll
      for (int r = 0; r < 4; ++r) {
        const int row = ob0 + 16 * mt + q * 4 + r;
        yg[row * N + col] = acc[mt][nt][r] + bias[row];
      }
    }
}

extern "C" void kernel_launch(void* const* d_in, const int* in_sizes, int n_in,
                              void* d_out, int out_size, void* d_ws, size_t ws_size,
                              hipStream_t stream) {
  const float* x    = (const float*)d_in[0];
  const float* S    = (const float*)d_in[1];
  const float* H    = (const float*)d_in[2];
  const float* bias = (const float*)d_in[3];
  float* y = (float*)d_out;

  const size_t STn = (size_t)B * T * E * N * N;   // 33.55M ushorts (64 MB)
  const size_t XTn = (size_t)B * T * N * F;       //  8.39M ushorts (16 MB)
  const size_t Wn  = (size_t)B * T * E * F * N;   // 16.78M ushorts (32 MB)
  ushort* ST = (ushort*)d_ws;
  ushort* xT = ST + STn;
  ushort* Wa = xT + XTn;
  ushort* Wb = Wa + Wn;
  ushort* Hb = Wb + Wn;                           // 32768 ushorts

  cvt_H   <<<32,        256, 0, stream>>>(H, Hb);
  cvt_X   <<<B * T,     256, 0, stream>>>(x, xT);
  cvt_S   <<<B * T * E, 256, 0, stream>>>(S, ST);
  gf_proj <<<B * T * E, 256, 0, stream>>>(xT, Hb, Wa, 3);
  gf_step <<<B * T * E, 256, 0, stream>>>(xT, ST, Hb, Wa, Wb, 2);
  gf_step <<<B * T * E, 256, 0, stream>>>(xT, ST, Hb, Wb, Wa, 1);
  gf_final<<<B * T,     256, 0, stream>>>(xT, ST, Hb, Wa, bias, y);
}